// Round 11
// baseline (140.202 us; speedup 1.0000x reference)
//
#include <hip/hip_runtime.h>
#include <math.h>

#define BB 64
#define II 1024
#define HH 1024

typedef float f4 __attribute__((ext_vector_type(4)));

// ws layout (floats)
#define WS_I     0
#define WS_F     64
#define WS_INVN  128
#define WS_DENOM 192
#define WS_O     256
#define WS_K     (256 + 65536)
#define WS_V     (256 + 2*65536)
#define WS_Q     (256 + 3*65536)

// ---------------- kernel 1: matvec partials, X AND W both staged coalesced ----------------
// grid = 8 k-chunks (128 cols) x 256 row-blocks = 2048 blocks, 256 threads (4 waves).
// Block stages X[64][128] (pad-129, 33 KB) AND W[16][128] (8 KB) into LDS with
// coalesced loads; compute reads X per-lane conflict-free (stride-129) and W
// wave-uniform broadcast. Weights read exactly once from HBM; X coalesced from
// L2 (64 MB total, 16x fewer txns than scattered). LDS 57.6 KB -> 2 blocks/CU.
// Partials -> pws[(kc*64+b)*4096 + gr] (c_out region, consumed by k_fin2).
__global__ __launch_bounds__(256) void k_mv(const float* __restrict__ input,
                                            const float* __restrict__ o_w,
                                            const float* __restrict__ kvq_w,
                                            float* __restrict__ pws) {
    __shared__ float xl[64 * 129];      // 33 KB, padded
    __shared__ float wl[16 * 128];      // 8 KB
    __shared__ float pl[16][4][64];     // 16 KB

    int t = threadIdx.x;
    int w = t >> 6, lane = t & 63;
    int kc = blockIdx.x >> 8;           // 0..7
    int rb = blockIdx.x & 255;          // 0..255
    int gr0 = rb * 16;
    const float* wbase = (gr0 < HH) ? (o_w + (size_t)gr0 * II)
                                    : (kvq_w + (size_t)(gr0 - HH) * II);

    // stage X[64][kc*128 .. +128] coalesced: 2048 f4, 8 per thread
#pragma unroll
    for (int rep = 0; rep < 8; ++rep) {
        int i = rep * 256 + t;
        int row = i >> 5;               // 0..63 (32 f4 per row)
        int c4  = i & 31;
        f4 v = *(const f4*)(input + (size_t)row * II + kc * 128 + c4 * 4);
        float* d = &xl[row * 129 + c4 * 4];
        d[0] = v.x; d[1] = v.y; d[2] = v.z; d[3] = v.w;
    }
    // stage W[16][128] coalesced: 512 f4, 2 per thread
#pragma unroll
    for (int rep = 0; rep < 2; ++rep) {
        int i = rep * 256 + t;
        int row = i >> 5;               // 0..15
        int c4  = i & 31;
        *(f4*)(&wl[row * 128 + c4 * 4]) =
            *(const f4*)(wbase + (size_t)row * II + kc * 128 + c4 * 4);
    }
    __syncthreads();

    // lane = batch: X sub-slice [w*32 .. +32] from LDS (stride-129 -> conflict-free)
    const float* xs = &xl[lane * 129 + w * 32];
    float xr[32];
#pragma unroll
    for (int j = 0; j < 32; ++j) xr[j] = xs[j];

    // 16 rows: wave-uniform W broadcast + 32 FMAs per row per lane
#pragma unroll 2
    for (int r = 0; r < 16; ++r) {
        const f4* wr4 = (const f4*)(&wl[r * 128 + w * 32]);
        float a0 = 0.f, a1 = 0.f;
#pragma unroll
        for (int j = 0; j < 8; j += 2) {
            f4 u = wr4[j], v = wr4[j + 1];
            a0 += u.x*xr[4*j+0] + u.y*xr[4*j+1] + u.z*xr[4*j+2] + u.w*xr[4*j+3];
            a1 += v.x*xr[4*j+4] + v.y*xr[4*j+5] + v.z*xr[4*j+6] + v.w*xr[4*j+7];
        }
        pl[r][w][lane] = a0 + a1;
    }
    __syncthreads();

    if (t < 64) {                       // wave 0: reduce 4 wave-partials, write pws
        int b = t;
        float* dst = pws + (((size_t)(kc * 64 + b)) << 12) + gr0;
#pragma unroll
        for (int r4 = 0; r4 < 4; ++r4) {
            f4 o;
            o.x = pl[4*r4+0][0][b] + pl[4*r4+0][1][b] + pl[4*r4+0][2][b] + pl[4*r4+0][3][b];
            o.y = pl[4*r4+1][0][b] + pl[4*r4+1][1][b] + pl[4*r4+1][2][b] + pl[4*r4+1][3][b];
            o.z = pl[4*r4+2][0][b] + pl[4*r4+2][1][b] + pl[4*r4+2][2][b] + pl[4*r4+2][3][b];
            o.w = pl[4*r4+3][0][b] + pl[4*r4+3][1][b] + pl[4*r4+3][2][b] + pl[4*r4+3][3][b];
            *(f4*)(dst + 4 * r4) = o;
        }
    }
}

// ---------------- kernel 2: gates + reduce partials + epilogue + denom ----------------
__global__ __launch_bounds__(256) void k_fin2(const float* __restrict__ pws,
                                              const float* __restrict__ input,
                                              const float* __restrict__ if_w,
                                              const float* __restrict__ if_b,
                                              const float* __restrict__ o_b,
                                              const float* __restrict__ kvq_b,
                                              const float* __restrict__ prev_n,
                                              float* __restrict__ ws,
                                              float* __restrict__ n_out) {
    int b = blockIdx.x;
    int t = threadIdx.x;
    int wv = t >> 6, lane = t & 63;

    // gates: d0 = x.if_w0, d1 = x.if_w1, ss = x.x
    f4 xv = *(const f4*)(input + (size_t)b * II + 4 * t);
    f4 g0 = *(const f4*)(if_w + 4 * t);
    f4 g1 = *(const f4*)(if_w + II + 4 * t);
    float d0 = xv.x*g0.x + xv.y*g0.y + xv.z*g0.z + xv.w*g0.w;
    float d1 = xv.x*g1.x + xv.y*g1.y + xv.z*g1.z + xv.w*g1.w;
    float ss = xv.x*xv.x + xv.y*xv.y + xv.z*xv.z + xv.w*xv.w;
#pragma unroll
    for (int off = 32; off > 0; off >>= 1) {
        d0 += __shfl_xor(d0, off);
        d1 += __shfl_xor(d1, off);
        ss += __shfl_xor(ss, off);
    }
    __shared__ float red[3][4];
    if (lane == 0) { red[0][wv] = d0; red[1][wv] = d1; red[2][wv] = ss; }
    __syncthreads();
    float td0 = red[0][0] + red[0][1] + red[0][2] + red[0][3];
    float td1 = red[1][0] + red[1][1] + red[1][2] + red[1][3];
    float tss = red[2][0] + red[2][1] + red[2][2] + red[2][3];
    float ib   = expf(td0 + if_b[0]);
    float fb   = expf(td1 + if_b[1]);
    float invn = 1.0f / sqrtf(tss);
    if (t == 0) {
        ws[WS_I + b]    = ib;
        ws[WS_F + b]    = fb;
        ws[WS_INVN + b] = invn;
    }

    // reduce 8 k-chunk partials per output element
    int hh = 4 * t;
    const float* pb = pws + ((size_t)b << 12);
    f4 d[4];
#pragma unroll
    for (int p = 0; p < 4; ++p) {
        f4 s = {0.f, 0.f, 0.f, 0.f};
#pragma unroll
        for (int kc = 0; kc < 8; ++kc)
            s += *(const f4*)(pb + ((size_t)kc << 18) + p * 1024 + hh);
        d[p] = s;
    }

    // o = sigmoid(d0 + o_b)
    f4 ob = *(const f4*)(o_b + hh);
    f4 o;
    o.x = 1.f / (1.f + expf(-(d[0].x + ob.x)));
    o.y = 1.f / (1.f + expf(-(d[0].y + ob.y)));
    o.z = 1.f / (1.f + expf(-(d[0].z + ob.z)));
    o.w = 1.f / (1.f + expf(-(d[0].w + ob.w)));
    *(f4*)(ws + WS_O + (size_t)b * HH + hh) = o;

    // k = d1*invn/32 + kvq_b[0]; n = f*prev_n + i*k
    f4 kbias = *(const f4*)(kvq_b + hh);
    f4 kv = d[1] * (invn * 0.03125f) + kbias;
    *(f4*)(ws + WS_K + (size_t)b * HH + hh) = kv;
    f4 pn = *(const f4*)(prev_n + (size_t)b * HH + hh);
    f4 nn = pn * fb + kv * ib;
    *(f4*)(n_out + (size_t)b * HH + hh) = nn;

    // v = d2*invn + kvq_b[1]
    f4 vb = *(const f4*)(kvq_b + HH + hh);
    f4 vv = d[2] * invn + vb;
    *(f4*)(ws + WS_V + (size_t)b * HH + hh) = vv;

    // q = d3*invn + kvq_b[2]
    f4 qb = *(const f4*)(kvq_b + 2 * HH + hh);
    f4 qv = d[3] * invn + qb;
    *(f4*)(ws + WS_Q + (size_t)b * HH + hh) = qv;

    // fused denom: block-reduce sum(n*q)
    float s = nn.x*qv.x + nn.y*qv.y + nn.z*qv.z + nn.w*qv.w;
#pragma unroll
    for (int off = 32; off > 0; off >>= 1) s += __shfl_xor(s, off);
    __syncthreads();               // red[] reuse hazard
    if (lane == 0) red[0][wv] = s;
    __syncthreads();
    if (t == 0)
        ws[WS_DENOM + b] = fmaxf(fabsf(red[0][0] + red[0][1] + red[0][2] + red[0][3]), 1.0f);
}

// ---------------- kernel 3: c update + fused readout h ----------------
// 8 rows/wave (one k/q read feeds 8 rows -> k/q L2 traffic halved), all 8
// prev_c loads issued upfront per column chunk (128 B/lane outstanding).
// nt load + nt store (measured-best policy). grid = 2048 blocks x 256 thr.
__global__ __launch_bounds__(256) void k_cup(const float* __restrict__ prev_c,
                                             const float* __restrict__ ws,
                                             float* __restrict__ c_out,
                                             float* __restrict__ h_out) {
    int wave = threadIdx.x >> 6, lane = threadIdx.x & 63;
    int g0 = (blockIdx.x * 4 + wave) * 8;    // first of 8 rows, all same batch
    int b = g0 >> 10;
    float fb = ws[WS_F + b], ib = ws[WS_I + b];
    float iv[8];
#pragma unroll
    for (int r = 0; r < 8; ++r) iv[r] = ib * ws[WS_V + g0 + r];
    const f4* pc = (const f4*)(prev_c + ((size_t)g0 << 10));
    f4*       co = (f4*)(c_out + ((size_t)g0 << 10));
    const float4* k4 = (const float4*)(ws + WS_K + (size_t)b * HH);
    const float4* q4 = (const float4*)(ws + WS_Q + (size_t)b * HH);
    float s[8] = {0.f, 0.f, 0.f, 0.f, 0.f, 0.f, 0.f, 0.f};
#pragma unroll
    for (int j = 0; j < 4; ++j) {
        int idx = lane + j * 64;
        float4 kv = k4[idx], qv = q4[idx];
        // issue all 8 row-loads upfront (8 x 16B outstanding per lane)
        f4 p0 = __builtin_nontemporal_load(&pc[idx]);
        f4 p1 = __builtin_nontemporal_load(&pc[idx + 256]);
        f4 p2 = __builtin_nontemporal_load(&pc[idx + 512]);
        f4 p3 = __builtin_nontemporal_load(&pc[idx + 768]);
        f4 p4 = __builtin_nontemporal_load(&pc[idx + 1024]);
        f4 p5 = __builtin_nontemporal_load(&pc[idx + 1280]);
        f4 p6 = __builtin_nontemporal_load(&pc[idx + 1536]);
        f4 p7 = __builtin_nontemporal_load(&pc[idx + 1792]);
        f4 c;
#define CUP_ROW(rr, pp)                                               \
        c.x = fb*pp.x + iv[rr]*kv.x; c.y = fb*pp.y + iv[rr]*kv.y;     \
        c.z = fb*pp.z + iv[rr]*kv.z; c.w = fb*pp.w + iv[rr]*kv.w;     \
        __builtin_nontemporal_store(c, &co[idx + rr*256]);            \
        s[rr] += c.x*qv.x + c.y*qv.y + c.z*qv.z + c.w*qv.w;
        CUP_ROW(0, p0) CUP_ROW(1, p1) CUP_ROW(2, p2) CUP_ROW(3, p3)
        CUP_ROW(4, p4) CUP_ROW(5, p5) CUP_ROW(6, p6) CUP_ROW(7, p7)
#undef CUP_ROW
    }
#pragma unroll
    for (int off = 32; off > 0; off >>= 1) {
#pragma unroll
        for (int r = 0; r < 8; ++r) s[r] += __shfl_xor(s[r], off);
    }
    if (lane == 0) {
        float inv_d = 1.0f / ws[WS_DENOM + b];
#pragma unroll
        for (int r = 0; r < 8; ++r)
            h_out[g0 + r] = ws[WS_O + g0 + r] * s[r] * inv_d;
    }
}

extern "C" void kernel_launch(void* const* d_in, const int* in_sizes, int n_in,
                              void* d_out, int out_size, void* d_ws, size_t ws_size,
                              hipStream_t stream) {
    const float* input  = (const float*)d_in[0];
    const float* prev_c = (const float*)d_in[2];
    const float* prev_n = (const float*)d_in[3];
    const float* if_w   = (const float*)d_in[4];
    const float* o_w    = (const float*)d_in[5];
    const float* kvq_w  = (const float*)d_in[6];
    const float* if_b   = (const float*)d_in[7];
    const float* o_b    = (const float*)d_in[8];
    const float* kvq_b  = (const float*)d_in[9];

    float* out   = (float*)d_out;
    float* h_out = out;                          // [B,H]
    float* c_out = out + 65536;                  // [B,H,H]
    float* n_out = out + 65536 + 67108864;       // [B,H]
    float* ws    = (float*)d_ws;
    float* pws   = c_out;                        // partials scratch inside c region

    k_mv  <<<2048, 256, 0, stream>>>(input, o_w, kvq_w, pws);
    k_fin2<<<BB, 256, 0, stream>>>(pws, input, if_w, if_b, o_b, kvq_b, prev_n, ws, n_out);
    k_cup <<<2048, 256, 0, stream>>>(prev_c, ws, c_out, h_out);
}

// Round 12
// 130.228 us; speedup vs baseline: 1.0766x; 1.0766x over previous
//
#include <hip/hip_runtime.h>
#include <math.h>

#define BB 64
#define II 1024
#define HH 1024

typedef float f4 __attribute__((ext_vector_type(4)));

// ws layout (floats)
#define WS_I     0
#define WS_F     64
#define WS_INVN  128
#define WS_DENOM 192
#define WS_O     256
#define WS_K     (256 + 65536)
#define WS_V     (256 + 2*65536)
#define WS_Q     (256 + 3*65536)
#define WS_XT    (256 + 4*65536)   // X transposed [k][b], 65536 floats

// ---------------- kernel 0: X transpose (coalesced read, tiny scatter write) ----------------
// 64 blocks x 256 threads; 256 KB total. Makes k_mv's X reads fully coalesced.
__global__ __launch_bounds__(256) void k_xt(const float* __restrict__ input,
                                            float* __restrict__ ws) {
    int b = blockIdx.x;
    int t = threadIdx.x;
#pragma unroll
    for (int rep = 0; rep < 4; ++rep) {
        int k = rep * 256 + t;
        ws[WS_XT + (size_t)k * 64 + b] = input[(size_t)b * II + k];
    }
}

// ---------------- kernel 1: matvec partials (R10 structure, X now coalesced via XT) ----
// grid = 4 k-chunks x 256 row-blocks = 1024 blocks, 256 threads (4 waves).
// W[16][256] staged coalesced into LDS (16 KB), read back wave-uniform
// (broadcast, conflict-free). X read COALESCED from XT[k][b]: 64 scalar
// loads/lane, 256 contiguous bytes per wave-instruction, L2-hot.
// Weights read exactly once from HBM. Partials -> pws[(kc*64+b)*4096 + gr].
__global__ __launch_bounds__(256) void k_mv3(const float* __restrict__ ws_in,
                                             const float* __restrict__ o_w,
                                             const float* __restrict__ kvq_w,
                                             float* __restrict__ pws) {
    __shared__ float wl[16 * 256];      // 16 KB
    __shared__ float pl[16][4][64];     // 16 KB

    int t = threadIdx.x;
    int w = t >> 6, lane = t & 63;
    int kc = blockIdx.x >> 8;           // 0..3
    int rb = blockIdx.x & 255;          // 0..255
    int gr0 = rb * 16;
    const float* wbase = (gr0 < HH) ? (o_w + (size_t)gr0 * II)
                                    : (kvq_w + (size_t)(gr0 - HH) * II);

    // stage W[16][256] coalesced: 1024 f4, 4 per thread
#pragma unroll
    for (int rep = 0; rep < 4; ++rep) {
        int i = rep * 256 + t;
        int row = i >> 6;               // 0..15
        int c4  = i & 63;               // 0..63
        f4 v = *(const f4*)(wbase + (size_t)row * II + kc * 256 + c4 * 4);
        *(f4*)(&wl[row * 256 + c4 * 4]) = v;
    }

    // X slice COALESCED from XT: lane = batch, 64 floats
    int k0 = kc * 256 + w * 64;
    const float* xt = ws_in + WS_XT + (size_t)k0 * 64 + lane;
    float xr[64];
#pragma unroll
    for (int j = 0; j < 64; ++j) xr[j] = xt[(size_t)j * 64];

    __syncthreads();

    // 16 rows: wave-uniform LDS broadcast + 64 FMAs per row per lane
#pragma unroll 2
    for (int r = 0; r < 16; ++r) {
        const f4* wr4 = (const f4*)(&wl[r * 256 + w * 64]);
        float a0 = 0.f, a1 = 0.f;
#pragma unroll
        for (int j = 0; j < 16; j += 2) {
            f4 u = wr4[j], v = wr4[j + 1];
            a0 += u.x*xr[4*j+0] + u.y*xr[4*j+1] + u.z*xr[4*j+2] + u.w*xr[4*j+3];
            a1 += v.x*xr[4*j+4] + v.y*xr[4*j+5] + v.z*xr[4*j+6] + v.w*xr[4*j+7];
        }
        pl[r][w][lane] = a0 + a1;
    }
    __syncthreads();

    if (t < 64) {                       // wave 0: reduce 4 wave-partials, write pws
        int b = t;
        float* dst = pws + (((size_t)(kc * 64 + b)) << 12) + gr0;
#pragma unroll
        for (int r4 = 0; r4 < 4; ++r4) {
            f4 o;
            o.x = pl[4*r4+0][0][b] + pl[4*r4+0][1][b] + pl[4*r4+0][2][b] + pl[4*r4+0][3][b];
            o.y = pl[4*r4+1][0][b] + pl[4*r4+1][1][b] + pl[4*r4+1][2][b] + pl[4*r4+1][3][b];
            o.z = pl[4*r4+2][0][b] + pl[4*r4+2][1][b] + pl[4*r4+2][2][b] + pl[4*r4+2][3][b];
            o.w = pl[4*r4+3][0][b] + pl[4*r4+3][1][b] + pl[4*r4+3][2][b] + pl[4*r4+3][3][b];
            *(f4*)(dst + 4 * r4) = o;
        }
    }
}

// ---------------- kernel 2: gates + reduce partials + epilogue + denom (R10) ----------------
__global__ __launch_bounds__(256) void k_fin2(const float* __restrict__ pws,
                                              const float* __restrict__ input,
                                              const float* __restrict__ if_w,
                                              const float* __restrict__ if_b,
                                              const float* __restrict__ o_b,
                                              const float* __restrict__ kvq_b,
                                              const float* __restrict__ prev_n,
                                              float* __restrict__ ws,
                                              float* __restrict__ n_out) {
    int b = blockIdx.x;
    int t = threadIdx.x;
    int wv = t >> 6, lane = t & 63;

    // gates: d0 = x.if_w0, d1 = x.if_w1, ss = x.x
    f4 xv = *(const f4*)(input + (size_t)b * II + 4 * t);
    f4 g0 = *(const f4*)(if_w + 4 * t);
    f4 g1 = *(const f4*)(if_w + II + 4 * t);
    float d0 = xv.x*g0.x + xv.y*g0.y + xv.z*g0.z + xv.w*g0.w;
    float d1 = xv.x*g1.x + xv.y*g1.y + xv.z*g1.z + xv.w*g1.w;
    float ss = xv.x*xv.x + xv.y*xv.y + xv.z*xv.z + xv.w*xv.w;
#pragma unroll
    for (int off = 32; off > 0; off >>= 1) {
        d0 += __shfl_xor(d0, off);
        d1 += __shfl_xor(d1, off);
        ss += __shfl_xor(ss, off);
    }
    __shared__ float red[3][4];
    if (lane == 0) { red[0][wv] = d0; red[1][wv] = d1; red[2][wv] = ss; }
    __syncthreads();
    float td0 = red[0][0] + red[0][1] + red[0][2] + red[0][3];
    float td1 = red[1][0] + red[1][1] + red[1][2] + red[1][3];
    float tss = red[2][0] + red[2][1] + red[2][2] + red[2][3];
    float ib   = expf(td0 + if_b[0]);
    float fb   = expf(td1 + if_b[1]);
    float invn = 1.0f / sqrtf(tss);
    if (t == 0) {
        ws[WS_I + b]    = ib;
        ws[WS_F + b]    = fb;
        ws[WS_INVN + b] = invn;
    }

    // reduce 4 k-chunk partials per output element
    int hh = 4 * t;
    const float* pb = pws + ((size_t)b << 12);
    f4 d[4];
#pragma unroll
    for (int p = 0; p < 4; ++p) {
        f4 s = {0.f, 0.f, 0.f, 0.f};
#pragma unroll
        for (int kc = 0; kc < 4; ++kc)
            s += *(const f4*)(pb + ((size_t)kc << 18) + p * 1024 + hh);
        d[p] = s;
    }

    // o = sigmoid(d0 + o_b)
    f4 ob = *(const f4*)(o_b + hh);
    f4 o;
    o.x = 1.f / (1.f + expf(-(d[0].x + ob.x)));
    o.y = 1.f / (1.f + expf(-(d[0].y + ob.y)));
    o.z = 1.f / (1.f + expf(-(d[0].z + ob.z)));
    o.w = 1.f / (1.f + expf(-(d[0].w + ob.w)));
    *(f4*)(ws + WS_O + (size_t)b * HH + hh) = o;

    // k = d1*invn/32 + kvq_b[0]; n = f*prev_n + i*k
    f4 kbias = *(const f4*)(kvq_b + hh);
    f4 kv = d[1] * (invn * 0.03125f) + kbias;
    *(f4*)(ws + WS_K + (size_t)b * HH + hh) = kv;
    f4 pn = *(const f4*)(prev_n + (size_t)b * HH + hh);
    f4 nn = pn * fb + kv * ib;
    *(f4*)(n_out + (size_t)b * HH + hh) = nn;

    // v = d2*invn + kvq_b[1]
    f4 vb = *(const f4*)(kvq_b + HH + hh);
    f4 vv = d[2] * invn + vb;
    *(f4*)(ws + WS_V + (size_t)b * HH + hh) = vv;

    // q = d3*invn + kvq_b[2]
    f4 qb = *(const f4*)(kvq_b + 2 * HH + hh);
    f4 qv = d[3] * invn + qb;
    *(f4*)(ws + WS_Q + (size_t)b * HH + hh) = qv;

    // fused denom: block-reduce sum(n*q)
    float s = nn.x*qv.x + nn.y*qv.y + nn.z*qv.z + nn.w*qv.w;
#pragma unroll
    for (int off = 32; off > 0; off >>= 1) s += __shfl_xor(s, off);
    __syncthreads();               // red[] reuse hazard
    if (lane == 0) red[0][wv] = s;
    __syncthreads();
    if (t == 0)
        ws[WS_DENOM + b] = fmaxf(fabsf(red[0][0] + red[0][1] + red[0][2] + red[0][3]), 1.0f);
}

// ---------------- kernel 3: c update + fused readout h (R10/R3-proven: nt+nt, 4 rows) ----
__global__ __launch_bounds__(256) void k_cup(const float* __restrict__ prev_c,
                                             const float* __restrict__ ws,
                                             float* __restrict__ c_out,
                                             float* __restrict__ h_out) {
    int wave = threadIdx.x >> 6, lane = threadIdx.x & 63;
    int g0 = (blockIdx.x * 4 + wave) * 4;    // first of 4 rows, all same batch
    int b = g0 >> 10;
    float fb = ws[WS_F + b], ib = ws[WS_I + b];
    float iv0 = ib * ws[WS_V + g0];
    float iv1 = ib * ws[WS_V + g0 + 1];
    float iv2 = ib * ws[WS_V + g0 + 2];
    float iv3 = ib * ws[WS_V + g0 + 3];
    const f4* pc = (const f4*)(prev_c + ((size_t)g0 << 10));
    f4*       co = (f4*)(c_out + ((size_t)g0 << 10));
    const float4* k4 = (const float4*)(ws + WS_K + (size_t)b * HH);
    const float4* q4 = (const float4*)(ws + WS_Q + (size_t)b * HH);
    float s0 = 0.f, s1 = 0.f, s2 = 0.f, s3 = 0.f;
#pragma unroll
    for (int j = 0; j < 4; ++j) {
        int idx = lane + j * 64;
        float4 kv = k4[idx], qv = q4[idx];
        f4 p, c;
        p = __builtin_nontemporal_load(&pc[idx]);
        c.x = fb*p.x + iv0*kv.x; c.y = fb*p.y + iv0*kv.y;
        c.z = fb*p.z + iv0*kv.z; c.w = fb*p.w + iv0*kv.w;
        __builtin_nontemporal_store(c, &co[idx]);
        s0 += c.x*qv.x + c.y*qv.y + c.z*qv.z + c.w*qv.w;

        p = __builtin_nontemporal_load(&pc[idx + 256]);
        c.x = fb*p.x + iv1*kv.x; c.y = fb*p.y + iv1*kv.y;
        c.z = fb*p.z + iv1*kv.z; c.w = fb*p.w + iv1*kv.w;
        __builtin_nontemporal_store(c, &co[idx + 256]);
        s1 += c.x*qv.x + c.y*qv.y + c.z*qv.z + c.w*qv.w;

        p = __builtin_nontemporal_load(&pc[idx + 512]);
        c.x = fb*p.x + iv2*kv.x; c.y = fb*p.y + iv2*kv.y;
        c.z = fb*p.z + iv2*kv.z; c.w = fb*p.w + iv2*kv.w;
        __builtin_nontemporal_store(c, &co[idx + 512]);
        s2 += c.x*qv.x + c.y*qv.y + c.z*qv.z + c.w*qv.w;

        p = __builtin_nontemporal_load(&pc[idx + 768]);
        c.x = fb*p.x + iv3*kv.x; c.y = fb*p.y + iv3*kv.y;
        c.z = fb*p.z + iv3*kv.z; c.w = fb*p.w + iv3*kv.w;
        __builtin_nontemporal_store(c, &co[idx + 768]);
        s3 += c.x*qv.x + c.y*qv.y + c.z*qv.z + c.w*qv.w;
    }
#pragma unroll
    for (int off = 32; off > 0; off >>= 1) {
        s0 += __shfl_xor(s0, off);
        s1 += __shfl_xor(s1, off);
        s2 += __shfl_xor(s2, off);
        s3 += __shfl_xor(s3, off);
    }
    if (lane == 0) {
        float inv_d = 1.0f / ws[WS_DENOM + b];
        h_out[g0]     = ws[WS_O + g0]     * s0 * inv_d;
        h_out[g0 + 1] = ws[WS_O + g0 + 1] * s1 * inv_d;
        h_out[g0 + 2] = ws[WS_O + g0 + 2] * s2 * inv_d;
        h_out[g0 + 3] = ws[WS_O + g0 + 3] * s3 * inv_d;
    }
}

extern "C" void kernel_launch(void* const* d_in, const int* in_sizes, int n_in,
                              void* d_out, int out_size, void* d_ws, size_t ws_size,
                              hipStream_t stream) {
    const float* input  = (const float*)d_in[0];
    const float* prev_c = (const float*)d_in[2];
    const float* prev_n = (const float*)d_in[3];
    const float* if_w   = (const float*)d_in[4];
    const float* o_w    = (const float*)d_in[5];
    const float* kvq_w  = (const float*)d_in[6];
    const float* if_b   = (const float*)d_in[7];
    const float* o_b    = (const float*)d_in[8];
    const float* kvq_b  = (const float*)d_in[9];

    float* out   = (float*)d_out;
    float* h_out = out;                          // [B,H]
    float* c_out = out + 65536;                  // [B,H,H]
    float* n_out = out + 65536 + 67108864;       // [B,H]
    float* ws    = (float*)d_ws;
    float* pws   = c_out;                        // partials scratch inside c region

    k_xt  <<<BB, 256, 0, stream>>>(input, ws);
    k_mv3 <<<1024, 256, 0, stream>>>(ws, o_w, kvq_w, pws);
    k_fin2<<<BB, 256, 0, stream>>>(pws, input, if_w, if_b, o_b, kvq_b, prev_n, ws, n_out);
    k_cup <<<4096, 256, 0, stream>>>(prev_c, ws, c_out, h_out);
}

// Round 13
// 124.870 us; speedup vs baseline: 1.1228x; 1.0429x over previous
//
#include <hip/hip_runtime.h>
#include <math.h>

#define BB 64
#define II 1024
#define HH 1024

typedef float f4 __attribute__((ext_vector_type(4)));

// ws layout (floats)
#define WS_I     0
#define WS_F     64
#define WS_INVN  128
#define WS_DENOM 192
#define WS_O     256
#define WS_K     (256 + 65536)
#define WS_V     (256 + 2*65536)
#define WS_Q     (256 + 3*65536)

// ---------------- kernel 1: matvec partials (R10 dataflow, 2x occupancy) ----------------
// grid = 4 k-chunks x 512 row-blocks = 2048 blocks, 256 threads (4 waves).
// 8 rows/block: W[8][256] staged coalesced into LDS (8 KB) + pl 8 KB = 16 KB
// -> 8 blocks/CU (32 waves/CU) for latency hiding. X per lane: 16 consecutive
// f4 (L1-efficient, lane = batch). W read back wave-uniform (broadcast).
// Weights read exactly once from HBM. Partials -> pws[(kc*64+b)*4096 + gr].
__global__ __launch_bounds__(256) void k_mv(const float* __restrict__ input,
                                            const float* __restrict__ o_w,
                                            const float* __restrict__ kvq_w,
                                            float* __restrict__ pws) {
    __shared__ float wl[8 * 256];       // 8 KB
    __shared__ float pl[8][4][64];      // 8 KB

    int t = threadIdx.x;
    int w = t >> 6, lane = t & 63;
    int kc = blockIdx.x >> 9;           // 0..3
    int rb = blockIdx.x & 511;          // 0..511
    int gr0 = rb * 8;
    const float* wbase = (gr0 < HH) ? (o_w + (size_t)gr0 * II)
                                    : (kvq_w + (size_t)(gr0 - HH) * II);

    // stage W[8][256] coalesced: 512 f4, 2 per thread
#pragma unroll
    for (int rep = 0; rep < 2; ++rep) {
        int i = rep * 256 + t;
        int row = i >> 6;               // 0..7
        int c4  = i & 63;               // 0..63
        f4 v = *(const f4*)(wbase + (size_t)row * II + kc * 256 + c4 * 4);
        *(f4*)(&wl[row * 256 + c4 * 4]) = v;
    }

    // X slice into registers: lane = batch, 16 consecutive f4 (L1-served)
    const f4* xs = (const f4*)(input + (size_t)lane * II + kc * 256 + w * 64);
    float xr[64];
#pragma unroll
    for (int j = 0; j < 16; ++j) {
        f4 v = xs[j];
        xr[4*j+0] = v.x; xr[4*j+1] = v.y; xr[4*j+2] = v.z; xr[4*j+3] = v.w;
    }

    __syncthreads();

    // 8 rows: wave-uniform LDS broadcast + 64 FMAs per row per lane
#pragma unroll 2
    for (int r = 0; r < 8; ++r) {
        const f4* wr4 = (const f4*)(&wl[r * 256 + w * 64]);
        float a0 = 0.f, a1 = 0.f;
#pragma unroll
        for (int j = 0; j < 16; j += 2) {
            f4 u = wr4[j], v = wr4[j + 1];
            a0 += u.x*xr[4*j+0] + u.y*xr[4*j+1] + u.z*xr[4*j+2] + u.w*xr[4*j+3];
            a1 += v.x*xr[4*j+4] + v.y*xr[4*j+5] + v.z*xr[4*j+6] + v.w*xr[4*j+7];
        }
        pl[r][w][lane] = a0 + a1;
    }
    __syncthreads();

    if (t < 64) {                       // wave 0: reduce 4 wave-partials, write pws
        int b = t;
        float* dst = pws + (((size_t)(kc * 64 + b)) << 12) + gr0;
#pragma unroll
        for (int r4 = 0; r4 < 2; ++r4) {
            f4 o;
            o.x = pl[4*r4+0][0][b] + pl[4*r4+0][1][b] + pl[4*r4+0][2][b] + pl[4*r4+0][3][b];
            o.y = pl[4*r4+1][0][b] + pl[4*r4+1][1][b] + pl[4*r4+1][2][b] + pl[4*r4+1][3][b];
            o.z = pl[4*r4+2][0][b] + pl[4*r4+2][1][b] + pl[4*r4+2][2][b] + pl[4*r4+2][3][b];
            o.w = pl[4*r4+3][0][b] + pl[4*r4+3][1][b] + pl[4*r4+3][2][b] + pl[4*r4+3][3][b];
            *(f4*)(dst + 4 * r4) = o;
        }
    }
}

// ---------------- kernel 2: gates + reduce partials + epilogue + denom (R10) ----------------
__global__ __launch_bounds__(256) void k_fin2(const float* __restrict__ pws,
                                              const float* __restrict__ input,
                                              const float* __restrict__ if_w,
                                              const float* __restrict__ if_b,
                                              const float* __restrict__ o_b,
                                              const float* __restrict__ kvq_b,
                                              const float* __restrict__ prev_n,
                                              float* __restrict__ ws,
                                              float* __restrict__ n_out) {
    int b = blockIdx.x;
    int t = threadIdx.x;
    int wv = t >> 6, lane = t & 63;

    // gates: d0 = x.if_w0, d1 = x.if_w1, ss = x.x
    f4 xv = *(const f4*)(input + (size_t)b * II + 4 * t);
    f4 g0 = *(const f4*)(if_w + 4 * t);
    f4 g1 = *(const f4*)(if_w + II + 4 * t);
    float d0 = xv.x*g0.x + xv.y*g0.y + xv.z*g0.z + xv.w*g0.w;
    float d1 = xv.x*g1.x + xv.y*g1.y + xv.z*g1.z + xv.w*g1.w;
    float ss = xv.x*xv.x + xv.y*xv.y + xv.z*xv.z + xv.w*xv.w;
#pragma unroll
    for (int off = 32; off > 0; off >>= 1) {
        d0 += __shfl_xor(d0, off);
        d1 += __shfl_xor(d1, off);
        ss += __shfl_xor(ss, off);
    }
    __shared__ float red[3][4];
    if (lane == 0) { red[0][wv] = d0; red[1][wv] = d1; red[2][wv] = ss; }
    __syncthreads();
    float td0 = red[0][0] + red[0][1] + red[0][2] + red[0][3];
    float td1 = red[1][0] + red[1][1] + red[1][2] + red[1][3];
    float tss = red[2][0] + red[2][1] + red[2][2] + red[2][3];
    float ib   = expf(td0 + if_b[0]);
    float fb   = expf(td1 + if_b[1]);
    float invn = 1.0f / sqrtf(tss);
    if (t == 0) {
        ws[WS_I + b]    = ib;
        ws[WS_F + b]    = fb;
        ws[WS_INVN + b] = invn;
    }

    // reduce 4 k-chunk partials per output element
    int hh = 4 * t;
    const float* pb = pws + ((size_t)b << 12);
    f4 d[4];
#pragma unroll
    for (int p = 0; p < 4; ++p) {
        f4 s = {0.f, 0.f, 0.f, 0.f};
#pragma unroll
        for (int kc = 0; kc < 4; ++kc)
            s += *(const f4*)(pb + ((size_t)kc << 18) + p * 1024 + hh);
        d[p] = s;
    }

    // o = sigmoid(d0 + o_b)
    f4 ob = *(const f4*)(o_b + hh);
    f4 o;
    o.x = 1.f / (1.f + expf(-(d[0].x + ob.x)));
    o.y = 1.f / (1.f + expf(-(d[0].y + ob.y)));
    o.z = 1.f / (1.f + expf(-(d[0].z + ob.z)));
    o.w = 1.f / (1.f + expf(-(d[0].w + ob.w)));
    *(f4*)(ws + WS_O + (size_t)b * HH + hh) = o;

    // k = d1*invn/32 + kvq_b[0]; n = f*prev_n + i*k
    f4 kbias = *(const f4*)(kvq_b + hh);
    f4 kv = d[1] * (invn * 0.03125f) + kbias;
    *(f4*)(ws + WS_K + (size_t)b * HH + hh) = kv;
    f4 pn = *(const f4*)(prev_n + (size_t)b * HH + hh);
    f4 nn = pn * fb + kv * ib;
    *(f4*)(n_out + (size_t)b * HH + hh) = nn;

    // v = d2*invn + kvq_b[1]
    f4 vb = *(const f4*)(kvq_b + HH + hh);
    f4 vv = d[2] * invn + vb;
    *(f4*)(ws + WS_V + (size_t)b * HH + hh) = vv;

    // q = d3*invn + kvq_b[2]
    f4 qb = *(const f4*)(kvq_b + 2 * HH + hh);
    f4 qv = d[3] * invn + qb;
    *(f4*)(ws + WS_Q + (size_t)b * HH + hh) = qv;

    // fused denom: block-reduce sum(n*q)
    float s = nn.x*qv.x + nn.y*qv.y + nn.z*qv.z + nn.w*qv.w;
#pragma unroll
    for (int off = 32; off > 0; off >>= 1) s += __shfl_xor(s, off);
    __syncthreads();               // red[] reuse hazard
    if (lane == 0) red[0][wv] = s;
    __syncthreads();
    if (t == 0)
        ws[WS_DENOM + b] = fmaxf(fabsf(red[0][0] + red[0][1] + red[0][2] + red[0][3]), 1.0f);
}

// ---------------- kernel 3: c update + fused readout h (R3/R10-proven: nt+nt, 4 rows) ----
__global__ __launch_bounds__(256) void k_cup(const float* __restrict__ prev_c,
                                             const float* __restrict__ ws,
                                             float* __restrict__ c_out,
                                             float* __restrict__ h_out) {
    int wave = threadIdx.x >> 6, lane = threadIdx.x & 63;
    int g0 = (blockIdx.x * 4 + wave) * 4;    // first of 4 rows, all same batch
    int b = g0 >> 10;
    float fb = ws[WS_F + b], ib = ws[WS_I + b];
    float iv0 = ib * ws[WS_V + g0];
    float iv1 = ib * ws[WS_V + g0 + 1];
    float iv2 = ib * ws[WS_V + g0 + 2];
    float iv3 = ib * ws[WS_V + g0 + 3];
    const f4* pc = (const f4*)(prev_c + ((size_t)g0 << 10));
    f4*       co = (f4*)(c_out + ((size_t)g0 << 10));
    const float4* k4 = (const float4*)(ws + WS_K + (size_t)b * HH);
    const float4* q4 = (const float4*)(ws + WS_Q + (size_t)b * HH);
    float s0 = 0.f, s1 = 0.f, s2 = 0.f, s3 = 0.f;
#pragma unroll
    for (int j = 0; j < 4; ++j) {
        int idx = lane + j * 64;
        float4 kv = k4[idx], qv = q4[idx];
        f4 p, c;
        p = __builtin_nontemporal_load(&pc[idx]);
        c.x = fb*p.x + iv0*kv.x; c.y = fb*p.y + iv0*kv.y;
        c.z = fb*p.z + iv0*kv.z; c.w = fb*p.w + iv0*kv.w;
        __builtin_nontemporal_store(c, &co[idx]);
        s0 += c.x*qv.x + c.y*qv.y + c.z*qv.z + c.w*qv.w;

        p = __builtin_nontemporal_load(&pc[idx + 256]);
        c.x = fb*p.x + iv1*kv.x; c.y = fb*p.y + iv1*kv.y;
        c.z = fb*p.z + iv1*kv.z; c.w = fb*p.w + iv1*kv.w;
        __builtin_nontemporal_store(c, &co[idx + 256]);
        s1 += c.x*qv.x + c.y*qv.y + c.z*qv.z + c.w*qv.w;

        p = __builtin_nontemporal_load(&pc[idx + 512]);
        c.x = fb*p.x + iv2*kv.x; c.y = fb*p.y + iv2*kv.y;
        c.z = fb*p.z + iv2*kv.z; c.w = fb*p.w + iv2*kv.w;
        __builtin_nontemporal_store(c, &co[idx + 512]);
        s2 += c.x*qv.x + c.y*qv.y + c.z*qv.z + c.w*qv.w;

        p = __builtin_nontemporal_load(&pc[idx + 768]);
        c.x = fb*p.x + iv3*kv.x; c.y = fb*p.y + iv3*kv.y;
        c.z = fb*p.z + iv3*kv.z; c.w = fb*p.w + iv3*kv.w;
        __builtin_nontemporal_store(c, &co[idx + 768]);
        s3 += c.x*qv.x + c.y*qv.y + c.z*qv.z + c.w*qv.w;
    }
#pragma unroll
    for (int off = 32; off > 0; off >>= 1) {
        s0 += __shfl_xor(s0, off);
        s1 += __shfl_xor(s1, off);
        s2 += __shfl_xor(s2, off);
        s3 += __shfl_xor(s3, off);
    }
    if (lane == 0) {
        float inv_d = 1.0f / ws[WS_DENOM + b];
        h_out[g0]     = ws[WS_O + g0]     * s0 * inv_d;
        h_out[g0 + 1] = ws[WS_O + g0 + 1] * s1 * inv_d;
        h_out[g0 + 2] = ws[WS_O + g0 + 2] * s2 * inv_d;
        h_out[g0 + 3] = ws[WS_O + g0 + 3] * s3 * inv_d;
    }
}

extern "C" void kernel_launch(void* const* d_in, const int* in_sizes, int n_in,
                              void* d_out, int out_size, void* d_ws, size_t ws_size,
                              hipStream_t stream) {
    const float* input  = (const float*)d_in[0];
    const float* prev_c = (const float*)d_in[2];
    const float* prev_n = (const float*)d_in[3];
    const float* if_w   = (const float*)d_in[4];
    const float* o_w    = (const float*)d_in[5];
    const float* kvq_w  = (const float*)d_in[6];
    const float* if_b   = (const float*)d_in[7];
    const float* o_b    = (const float*)d_in[8];
    const float* kvq_b  = (const float*)d_in[9];

    float* out   = (float*)d_out;
    float* h_out = out;                          // [B,H]
    float* c_out = out + 65536;                  // [B,H,H]
    float* n_out = out + 65536 + 67108864;       // [B,H]
    float* ws    = (float*)d_ws;
    float* pws   = c_out;                        // partials scratch inside c region

    k_mv  <<<2048, 256, 0, stream>>>(input, o_w, kvq_w, pws);
    k_fin2<<<BB, 256, 0, stream>>>(pws, input, if_w, if_b, o_b, kvq_b, prev_n, ws, n_out);
    k_cup <<<4096, 256, 0, stream>>>(prev_c, ws, c_out, h_out);
}

// Round 14
// 118.456 us; speedup vs baseline: 1.1836x; 1.0541x over previous
//
#include <hip/hip_runtime.h>
#include <math.h>

#define BB 64
#define II 1024
#define HH 1024

typedef float f4 __attribute__((ext_vector_type(4)));

// ws layout (floats)
#define WS_I     0
#define WS_F     64
#define WS_INVN  128
#define WS_DENOM 192
#define WS_O     256
#define WS_K     (256 + 65536)
#define WS_V     (256 + 2*65536)
#define WS_Q     (256 + 3*65536)

// ---------------- kernel 1: matvec partials (R10-proven: W via LDS, X in regs) ----------------
// grid = 4 k-chunks x 256 row-blocks = 1024 blocks, 256 threads (4 waves).
// Block stages W[16 rows][256 k] into LDS coalesced (16 KB); compute reads W
// wave-uniform broadcast. X per lane (lane = batch): 16 consecutive f4,
// L1/L2-served. Weights read exactly once from HBM.
// Partials -> pws[(kc*64+b)*4096 + gr] (c_out region, consumed by k_fin2).
__global__ __launch_bounds__(256) void k_mv(const float* __restrict__ input,
                                            const float* __restrict__ o_w,
                                            const float* __restrict__ kvq_w,
                                            float* __restrict__ pws) {
    __shared__ float wl[16 * 256];      // 16 KB
    __shared__ float pl[16][4][64];     // 16 KB

    int t = threadIdx.x;
    int w = t >> 6, lane = t & 63;
    int kc = blockIdx.x >> 8;           // 0..3
    int rb = blockIdx.x & 255;          // 0..255
    int gr0 = rb * 16;
    const float* wbase = (gr0 < HH) ? (o_w + (size_t)gr0 * II)
                                    : (kvq_w + (size_t)(gr0 - HH) * II);

    // stage W[16][256] coalesced: 1024 f4, 4 per thread
#pragma unroll
    for (int rep = 0; rep < 4; ++rep) {
        int i = rep * 256 + t;
        int row = i >> 6;               // 0..15
        int c4  = i & 63;               // 0..63
        f4 v = *(const f4*)(wbase + (size_t)row * II + kc * 256 + c4 * 4);
        *(f4*)(&wl[row * 256 + c4 * 4]) = v;
    }

    // X slice into registers: lane = batch, 16 consecutive f4 (L1/L2-served)
    const f4* xs = (const f4*)(input + (size_t)lane * II + kc * 256 + w * 64);
    f4 xr[16];
#pragma unroll
    for (int j = 0; j < 16; ++j) xr[j] = xs[j];

    __syncthreads();

    // 16 rows: wave-uniform LDS broadcast + 64 FMAs per row per lane
#pragma unroll 2
    for (int r = 0; r < 16; ++r) {
        const f4* wr4 = (const f4*)(&wl[r * 256 + w * 64]);
        float a0 = 0.f, a1 = 0.f;
#pragma unroll
        for (int j = 0; j < 16; j += 2) {
            f4 u = wr4[j], v = wr4[j + 1];
            a0 += u.x*xr[j].x + u.y*xr[j].y + u.z*xr[j].z + u.w*xr[j].w;
            a1 += v.x*xr[j+1].x + v.y*xr[j+1].y + v.z*xr[j+1].z + v.w*xr[j+1].w;
        }
        pl[r][w][lane] = a0 + a1;
    }
    __syncthreads();

    if (t < 64) {                       // wave 0: reduce 4 wave-partials, write pws
        int b = t;
        float* dst = pws + (((size_t)(kc * 64 + b)) << 12) + gr0;
#pragma unroll
        for (int r4 = 0; r4 < 4; ++r4) {
            f4 o;
            o.x = pl[4*r4+0][0][b] + pl[4*r4+0][1][b] + pl[4*r4+0][2][b] + pl[4*r4+0][3][b];
            o.y = pl[4*r4+1][0][b] + pl[4*r4+1][1][b] + pl[4*r4+1][2][b] + pl[4*r4+1][3][b];
            o.z = pl[4*r4+2][0][b] + pl[4*r4+2][1][b] + pl[4*r4+2][2][b] + pl[4*r4+2][3][b];
            o.w = pl[4*r4+3][0][b] + pl[4*r4+3][1][b] + pl[4*r4+3][2][b] + pl[4*r4+3][3][b];
            *(f4*)(dst + 4 * r4) = o;
        }
    }
}

// ---------------- kernel 2: gates + reduce partials + epilogue + denom (R10) ----------------
__global__ __launch_bounds__(256) void k_fin2(const float* __restrict__ pws,
                                              const float* __restrict__ input,
                                              const float* __restrict__ if_w,
                                              const float* __restrict__ if_b,
                                              const float* __restrict__ o_b,
                                              const float* __restrict__ kvq_b,
                                              const float* __restrict__ prev_n,
                                              float* __restrict__ ws,
                                              float* __restrict__ n_out) {
    int b = blockIdx.x;
    int t = threadIdx.x;
    int wv = t >> 6, lane = t & 63;

    // gates: d0 = x.if_w0, d1 = x.if_w1, ss = x.x
    f4 xv = *(const f4*)(input + (size_t)b * II + 4 * t);
    f4 g0 = *(const f4*)(if_w + 4 * t);
    f4 g1 = *(const f4*)(if_w + II + 4 * t);
    float d0 = xv.x*g0.x + xv.y*g0.y + xv.z*g0.z + xv.w*g0.w;
    float d1 = xv.x*g1.x + xv.y*g1.y + xv.z*g1.z + xv.w*g1.w;
    float ss = xv.x*xv.x + xv.y*xv.y + xv.z*xv.z + xv.w*xv.w;
#pragma unroll
    for (int off = 32; off > 0; off >>= 1) {
        d0 += __shfl_xor(d0, off);
        d1 += __shfl_xor(d1, off);
        ss += __shfl_xor(ss, off);
    }
    __shared__ float red[3][4];
    if (lane == 0) { red[0][wv] = d0; red[1][wv] = d1; red[2][wv] = ss; }
    __syncthreads();
    float td0 = red[0][0] + red[0][1] + red[0][2] + red[0][3];
    float td1 = red[1][0] + red[1][1] + red[1][2] + red[1][3];
    float tss = red[2][0] + red[2][1] + red[2][2] + red[2][3];
    float ib   = expf(td0 + if_b[0]);
    float fb   = expf(td1 + if_b[1]);
    float invn = 1.0f / sqrtf(tss);
    if (t == 0) {
        ws[WS_I + b]    = ib;
        ws[WS_F + b]    = fb;
        ws[WS_INVN + b] = invn;
    }

    // reduce 4 k-chunk partials per output element
    int hh = 4 * t;
    const float* pb = pws + ((size_t)b << 12);
    f4 d[4];
#pragma unroll
    for (int p = 0; p < 4; ++p) {
        f4 s = {0.f, 0.f, 0.f, 0.f};
#pragma unroll
        for (int kc = 0; kc < 4; ++kc)
            s += *(const f4*)(pb + ((size_t)kc << 18) + p * 1024 + hh);
        d[p] = s;
    }

    // o = sigmoid(d0 + o_b)
    f4 ob = *(const f4*)(o_b + hh);
    f4 o;
    o.x = 1.f / (1.f + expf(-(d[0].x + ob.x)));
    o.y = 1.f / (1.f + expf(-(d[0].y + ob.y)));
    o.z = 1.f / (1.f + expf(-(d[0].z + ob.z)));
    o.w = 1.f / (1.f + expf(-(d[0].w + ob.w)));
    *(f4*)(ws + WS_O + (size_t)b * HH + hh) = o;

    // k = d1*invn/32 + kvq_b[0]; n = f*prev_n + i*k
    f4 kbias = *(const f4*)(kvq_b + hh);
    f4 kv = d[1] * (invn * 0.03125f) + kbias;
    *(f4*)(ws + WS_K + (size_t)b * HH + hh) = kv;
    f4 pn = *(const f4*)(prev_n + (size_t)b * HH + hh);
    f4 nn = pn * fb + kv * ib;
    *(f4*)(n_out + (size_t)b * HH + hh) = nn;

    // v = d2*invn + kvq_b[1]
    f4 vb = *(const f4*)(kvq_b + HH + hh);
    f4 vv = d[2] * invn + vb;
    *(f4*)(ws + WS_V + (size_t)b * HH + hh) = vv;

    // q = d3*invn + kvq_b[2]
    f4 qb = *(const f4*)(kvq_b + 2 * HH + hh);
    f4 qv = d[3] * invn + qb;
    *(f4*)(ws + WS_Q + (size_t)b * HH + hh) = qv;

    // fused denom: block-reduce sum(n*q)
    float s = nn.x*qv.x + nn.y*qv.y + nn.z*qv.z + nn.w*qv.w;
#pragma unroll
    for (int off = 32; off > 0; off >>= 1) s += __shfl_xor(s, off);
    __syncthreads();               // red[] reuse hazard
    if (lane == 0) red[0][wv] = s;
    __syncthreads();
    if (t == 0)
        ws[WS_DENOM + b] = fmaxf(fabsf(red[0][0] + red[0][1] + red[0][2] + red[0][3]), 1.0f);
}

// ---------------- kernel 3: c update + fused readout h -- 1 ROW PER WAVE ----------------
// A/B vs R10's 4-row cup (95.4 us measured): maximize memory-level parallelism.
// grid = 16384 blocks x 256 thr; wave = one c-row; 4 independent nt load/store
// pairs per lane, fully unrolled (all loads issuable before first dependent use).
__global__ __launch_bounds__(256) void k_cup(const float* __restrict__ prev_c,
                                             const float* __restrict__ ws,
                                             float* __restrict__ c_out,
                                             float* __restrict__ h_out) {
    int wave = threadIdx.x >> 6, lane = threadIdx.x & 63;
    int g = blockIdx.x * 4 + wave;           // row id in [0, 65536) = b*1024 + r
    int b = g >> 10;
    float fb = ws[WS_F + b];
    float iv = ws[WS_I + b] * ws[WS_V + g];
    const f4* pc = (const f4*)(prev_c + ((size_t)g << 10));
    f4*       co = (f4*)(c_out + ((size_t)g << 10));
    const float4* k4 = (const float4*)(ws + WS_K + (size_t)b * HH);
    const float4* q4 = (const float4*)(ws + WS_Q + (size_t)b * HH);
    float s = 0.f;
#pragma unroll
    for (int j = 0; j < 4; ++j) {
        int idx = lane + j * 64;
        float4 kv = k4[idx], qv = q4[idx];
        f4 p = __builtin_nontemporal_load(&pc[idx]);
        f4 c;
        c.x = fb*p.x + iv*kv.x; c.y = fb*p.y + iv*kv.y;
        c.z = fb*p.z + iv*kv.z; c.w = fb*p.w + iv*kv.w;
        __builtin_nontemporal_store(c, &co[idx]);
        s += c.x*qv.x + c.y*qv.y + c.z*qv.z + c.w*qv.w;
    }
#pragma unroll
    for (int off = 32; off > 0; off >>= 1) s += __shfl_xor(s, off);
    if (lane == 0)
        h_out[g] = ws[WS_O + g] * s / ws[WS_DENOM + b];
}

extern "C" void kernel_launch(void* const* d_in, const int* in_sizes, int n_in,
                              void* d_out, int out_size, void* d_ws, size_t ws_size,
                              hipStream_t stream) {
    const float* input  = (const float*)d_in[0];
    const float* prev_c = (const float*)d_in[2];
    const float* prev_n = (const float*)d_in[3];
    const float* if_w   = (const float*)d_in[4];
    const float* o_w    = (const float*)d_in[5];
    const float* kvq_w  = (const float*)d_in[6];
    const float* if_b   = (const float*)d_in[7];
    const float* o_b    = (const float*)d_in[8];
    const float* kvq_b  = (const float*)d_in[9];

    float* out   = (float*)d_out;
    float* h_out = out;                          // [B,H]
    float* c_out = out + 65536;                  // [B,H,H]
    float* n_out = out + 65536 + 67108864;       // [B,H]
    float* ws    = (float*)d_ws;
    float* pws   = c_out;                        // partials scratch inside c region

    k_mv  <<<1024, 256, 0, stream>>>(input, o_w, kvq_w, pws);
    k_fin2<<<BB, 256, 0, stream>>>(pws, input, if_w, if_b, o_b, kvq_b, prev_n, ws, n_out);
    k_cup <<<16384, 256, 0, stream>>>(prev_c, ws, c_out, h_out);
}